// Round 8
// baseline (573.378 us; speedup 1.0000x reference)
//
#include <hip/hip_runtime.h>

// B=2, N=2048, E=2048, H=16, D=128.
// Pipeline: cast fp32->bf16; gemm_qk (256 blocks, 256x256, 4 quadrant-phases,
// T1/T2/T4/T5) -> q|k; gemm_thin<0> (256x128, deepened 4-phase) -> V
// transposed vt[b][f][n]; SPLIT-K flash attention (768 blocks, K-only LDS
// staging [32 KiB -> 4 blocks/CU], V read per-wave direct from global/L1,
// partials in f32 scratch) + merge kernel; gemm_thin<1> -> out.

typedef __bf16 bf16;
typedef bf16 bf16x2 __attribute__((ext_vector_type(2)));
typedef bf16 bf16x4 __attribute__((ext_vector_type(4)));
typedef bf16 bf16x8 __attribute__((ext_vector_type(8)));
typedef float f32x4 __attribute__((ext_vector_type(4)));
typedef float f32x16 __attribute__((ext_vector_type(16)));

typedef const __attribute__((address_space(1))) void cg_void;
typedef __attribute__((address_space(3))) void lds_void;

#define MFMA16(a, b, c) __builtin_amdgcn_mfma_f32_16x16x32_bf16((a), (b), (c), 0, 0, 0)
#define MFMA32(a, b, c) __builtin_amdgcn_mfma_f32_32x32x16_bf16((a), (b), (c), 0, 0, 0)

__device__ __forceinline__ void async_load16(const bf16* g, bf16* l) {
  __builtin_amdgcn_global_load_lds((cg_void*)g, (lds_void*)l, 16, 0, 0);
}

// ---------------- merged cast fp32 -> bf16 ----------------
__global__ __launch_bounds__(256) void cast_all_kernel(
    const float* __restrict__ x, const float* __restrict__ wq,
    const float* __restrict__ wkv, const float* __restrict__ wout,
    bf16* __restrict__ xb, bf16* __restrict__ wqkvb, bf16* __restrict__ woutb) {
  long i = (long)blockIdx.x * 256 + threadIdx.x;  // 8-elem chunks
  const float* src; bf16* dst; long off;
  if (i < 1048576)      { src = x;    dst = xb;            off = i; }
  else if (i < 2621440) { src = wq;   dst = wqkvb;         off = i - 1048576;
                          if (off >= 524288) { src = wkv; dst = wqkvb + 4194304; off -= 524288; } }
  else                  { src = wout; dst = woutb;         off = i - 2621440; }
  float4 f0 = ((const float4*)src)[2 * off];
  float4 f1 = ((const float4*)src)[2 * off + 1];
  bf16x8 o;
  o[0] = (bf16)f0.x; o[1] = (bf16)f0.y; o[2] = (bf16)f0.z; o[3] = (bf16)f0.w;
  o[4] = (bf16)f1.x; o[5] = (bf16)f1.y; o[6] = (bf16)f1.z; o[7] = (bf16)f1.w;
  ((bf16x8*)dst)[off] = o;
}

// Staging macros (use locals Ag/Bg/ldsA/ldsB). LDS dest is linear
// (global_load_lds writes base+lane*16); the XOR swizzle (16B chunk ^= row&7)
// is pre-applied on the GLOBAL source address.
#define STAGE_A(bufi, h, tt) do {                              \
    const bf16* g_ = Ag + (h) * 262144 + (tt) * 64;            \
    bf16* d_ = ldsA + (bufi) * 16384 + (h) * 8192;             \
    async_load16(g_, d_);                                      \
    async_load16(g_ + 131072, d_ + 4096);                      \
  } while (0)
#define STAGE_B(bufi, h, tt) do {                              \
    const bf16* g_ = Bg + (h) * 262144 + (tt) * 64;            \
    bf16* d_ = ldsB + (bufi) * 16384 + (h) * 8192;             \
    async_load16(g_, d_);                                      \
    async_load16(g_ + 131072, d_ + 4096);                      \
  } while (0)
#define STAGE_BS(bufi, tt) do {                                \
    const bf16* g_ = Bg + (tt) * 64;                           \
    bf16* d_ = ldsB + (bufi) * 8192;                           \
    async_load16(g_, d_);                                      \
    async_load16(g_ + 131072, d_ + 4096);                      \
  } while (0)

// ---------------- q|k GEMM: 256x256 tile, 4 quadrant-phases/K-tile ----------
// (unchanged — control)
__global__ __launch_bounds__(512, 2)
void gemm_qk_8phase(const bf16* __restrict__ A, const bf16* __restrict__ B,
                    bf16* __restrict__ qk) {
  __shared__ __attribute__((aligned(16))) bf16 sm[2][2][256][64];  // 128 KiB
  const int tid = threadIdx.x;
  const int lane = tid & 63;
  const int wid = tid >> 6;
  const int quad = lane >> 4, l15 = lane & 15;
  const int wr = wid >> 2, wc = wid & 3;   // 2M x 4N waves; wave tile 128x64

  const int lb = (blockIdx.x & 7) * 32 + (blockIdx.x >> 3);
  const int bm = lb >> 4, bn = lb & 15;
  const int m0 = bm * 256, n0 = bn * 256;

  const int srow = tid >> 3;
  const int kswz8 = ((tid & 7) ^ (srow & 7)) * 8;
  const bf16* Ag = A + (size_t)(m0 + srow) * 2048 + kswz8;
  const bf16* Bg = B + (size_t)(n0 + srow) * 2048 + kswz8;
  bf16* ldsA = &sm[0][0][0][0] + tid * 8;
  bf16* ldsB = &sm[1][0][0][0] + tid * 8;

  f32x4 acc[8][4];
#pragma unroll
  for (int i = 0; i < 8; ++i)
#pragma unroll
    for (int j = 0; j < 4; ++j) acc[i][j] = {0.f, 0.f, 0.f, 0.f};

  const int r7 = l15 & 7;
  const int c0 = (quad ^ r7) * 8;        // ks=0 swizzled chunk
  const int c1 = ((4 + quad) ^ r7) * 8;  // ks=1
  const int arow = (wr * 128 + l15) * 64;
  const int brow = (wc * 64 + l15) * 64;

  STAGE_A(0, 0, 0); STAGE_A(0, 1, 0); STAGE_B(0, 0, 0); STAGE_B(0, 1, 0);
  STAGE_A(1, 0, 1); STAGE_A(1, 1, 1);
  asm volatile("s_waitcnt vmcnt(4)" ::: "memory");  // tile0 landed
  __builtin_amdgcn_s_barrier();

  for (int t = 0; t < 32; ++t) {
    const int cur = t & 1;
    const bf16* as = &sm[0][0][0][0] + cur * 16384;
    const bf16* bs = &sm[1][0][0][0] + cur * 16384;
    bf16x8 a0[4][2], a1[4][2], b0[2][2], b1[2][2];

    // ---- ph0: q(0,0) ----
#pragma unroll
    for (int i = 0; i < 4; ++i) {
      a0[i][0] = *(const bf16x8*)(as + arow + i * 1024 + c0);
      a0[i][1] = *(const bf16x8*)(as + arow + i * 1024 + c1);
    }
#pragma unroll
    for (int j = 0; j < 2; ++j) {
      b0[j][0] = *(const bf16x8*)(bs + brow + j * 1024 + c0);
      b0[j][1] = *(const bf16x8*)(bs + brow + j * 1024 + c1);
    }
    if (t < 31) STAGE_B(1 - cur, 0, t + 1);
    asm volatile("s_waitcnt lgkmcnt(8)" ::: "memory");
    __builtin_amdgcn_s_barrier();
    asm volatile("s_waitcnt lgkmcnt(0)" ::: "memory");
    __builtin_amdgcn_s_setprio(1);
#pragma unroll
    for (int ks = 0; ks < 2; ++ks)
#pragma unroll
      for (int i = 0; i < 4; ++i)
#pragma unroll
        for (int j = 0; j < 2; ++j) acc[i][j] = MFMA16(a0[i][ks], b0[j][ks], acc[i][j]);
    __builtin_amdgcn_s_setprio(0);
    __builtin_amdgcn_s_barrier();

    // ---- ph1: q(0,1) ----
#pragma unroll
    for (int j = 0; j < 2; ++j) {
      b1[j][0] = *(const bf16x8*)(bs + brow + (2 + j) * 1024 + c0);
      b1[j][1] = *(const bf16x8*)(bs + brow + (2 + j) * 1024 + c1);
    }
    if (t < 31) STAGE_B(1 - cur, 1, t + 1);
    __builtin_amdgcn_s_barrier();
    asm volatile("s_waitcnt lgkmcnt(0)" ::: "memory");
    __builtin_amdgcn_s_setprio(1);
#pragma unroll
    for (int ks = 0; ks < 2; ++ks)
#pragma unroll
      for (int i = 0; i < 4; ++i)
#pragma unroll
        for (int j = 0; j < 2; ++j) acc[i][2 + j] = MFMA16(a0[i][ks], b1[j][ks], acc[i][2 + j]);
    __builtin_amdgcn_s_setprio(0);
    __builtin_amdgcn_s_barrier();

    // ---- ph2: q(1,0) ----
#pragma unroll
    for (int i = 0; i < 4; ++i) {
      a1[i][0] = *(const bf16x8*)(as + arow + (4 + i) * 1024 + c0);
      a1[i][1] = *(const bf16x8*)(as + arow + (4 + i) * 1024 + c1);
    }
    __builtin_amdgcn_s_barrier();
    asm volatile("s_waitcnt lgkmcnt(0)" ::: "memory");
    __builtin_amdgcn_s_setprio(1);
#pragma unroll
    for (int ks = 0; ks < 2; ++ks)
#pragma unroll
      for (int i = 0; i < 4; ++i)
#pragma unroll
        for (int j = 0; j < 2; ++j) acc[4 + i][j] = MFMA16(a1[i][ks], b0[j][ks], acc[4 + i][j]);
    __builtin_amdgcn_s_setprio(0);
    __builtin_amdgcn_s_barrier();

    // ---- ph3: q(1,1) + boundary ----
    __builtin_amdgcn_s_setprio(1);
#pragma unroll
    for (int ks = 0; ks < 2; ++ks)
#pragma unroll
      for (int i = 0; i < 4; ++i)
#pragma unroll
        for (int j = 0; j < 2; ++j) acc[4 + i][2 + j] = MFMA16(a1[i][ks], b1[j][ks], acc[4 + i][2 + j]);
    __builtin_amdgcn_s_setprio(0);
    if (t < 30) {
      STAGE_A(cur, 0, t + 2); STAGE_A(cur, 1, t + 2);
      asm volatile("s_waitcnt vmcnt(4)" ::: "memory");  // t+1 landed
      __builtin_amdgcn_s_barrier();
    } else if (t == 30) {
      asm volatile("s_waitcnt vmcnt(0)" ::: "memory");
      __builtin_amdgcn_s_barrier();
    }
  }

#pragma unroll
  for (int i = 0; i < 8; ++i)
#pragma unroll
    for (int r = 0; r < 4; ++r) {
      const size_t base = (size_t)(m0 + wr * 128 + i * 16 + quad * 4 + r) * 4096
                        + n0 + wc * 64 + l15;
#pragma unroll
      for (int j = 0; j < 4; ++j) qk[base + j * 16] = (bf16)acc[i][j][r];
    }
}

// ---------------- thin GEMM: 256x128, 2-K-tile deepened 4-phase -------------
// (unchanged — control)
template <int OUTMODE>
__global__ __launch_bounds__(512, 2)
void gemm_thin(const bf16* __restrict__ A, const bf16* __restrict__ B,
               bf16* __restrict__ vt, float* __restrict__ C) {
  __shared__ __attribute__((aligned(16))) bf16 smA[2][256][64];  // 64 KiB
  __shared__ __attribute__((aligned(16))) bf16 smB[2][128][64];  // 32 KiB
  const int tid = threadIdx.x;
  const int lane = tid & 63;
  const int wid = tid >> 6;
  const int quad = lane >> 4, l15 = lane & 15;
  const int wr = wid >> 1, wc = wid & 1;   // 4M x 2N waves; wave tile 64x64

  const int lb = (blockIdx.x & 7) * 32 + (blockIdx.x >> 3);
  const int bm = lb >> 4, bn = lb & 15;
  const int m0 = bm * 256, n0 = bn * 128;

  const int srow = tid >> 3;
  const int kswz8 = ((tid & 7) ^ (srow & 7)) * 8;
  const bf16* Ag = A + (size_t)(m0 + srow) * 2048 + kswz8;
  const bf16* Bg = B + (size_t)(n0 + srow) * 2048 + kswz8;
  bf16* ldsA = &smA[0][0][0] + tid * 8;
  bf16* ldsB = &smB[0][0][0] + tid * 8;

  f32x4 acc[4][4];
#pragma unroll
  for (int i = 0; i < 4; ++i)
#pragma unroll
    for (int j = 0; j < 4; ++j) acc[i][j] = {0.f, 0.f, 0.f, 0.f};

  const int r7 = l15 & 7;
  const int c0 = (quad ^ r7) * 8;        // ks=0 swizzled chunk
  const int c1 = ((4 + quad) ^ r7) * 8;  // ks=1
  const int arow = (wr * 64 + l15) * 64;
  const int brow = (wc * 64 + l15) * 64;

  STAGE_A(0, 0, 0); STAGE_A(0, 1, 0); STAGE_BS(0, 0);
  STAGE_A(1, 0, 1); STAGE_A(1, 1, 1); STAGE_BS(1, 1);
  asm volatile("s_waitcnt vmcnt(6)" ::: "memory");
  __builtin_amdgcn_s_barrier();

  const bf16* ae = &smA[0][0][0];
  const bf16* ao = &smA[1][0][0];
  const bf16* be = &smB[0][0][0];
  const bf16* bo = &smB[1][0][0];

  for (int u = 0; u < 16; ++u) {
    const int e = 2 * u;
    const bool st = (u < 15);
    bf16x8 afe[4][2], bfe[4][2], afo[4][2], bfo[4][2];

    // ---- ph0 ----
#pragma unroll
    for (int i = 0; i < 4; ++i) {
      afe[i][0] = *(const bf16x8*)(ae + arow + i * 1024 + c0);
      afe[i][1] = *(const bf16x8*)(ae + arow + i * 1024 + c1);
    }
#pragma unroll
    for (int j = 0; j < 4; ++j)
      bfe[j][0] = *(const bf16x8*)(be + brow + j * 1024 + c0);
    asm volatile("s_waitcnt lgkmcnt(0)" ::: "memory");
    __builtin_amdgcn_s_barrier();
    __builtin_amdgcn_s_setprio(1);
#pragma unroll
    for (int i = 0; i < 4; ++i)
#pragma unroll
      for (int j = 0; j < 4; ++j) acc[i][j] = MFMA16(afe[i][0], bfe[j][0], acc[i][j]);
    __builtin_amdgcn_s_setprio(0);
    __builtin_amdgcn_s_barrier();

    // ---- ph1 ----
#pragma unroll
    for (int j = 0; j < 4; ++j)
      bfe[j][1] = *(const bf16x8*)(be + brow + j * 1024 + c1);
    asm volatile("s_waitcnt lgkmcnt(0)" ::: "memory");
    __builtin_amdgcn_s_barrier();
    if (st) { STAGE_A(0, 0, e + 2); STAGE_A(0, 1, e + 2); }
    __builtin_amdgcn_s_setprio(1);
#pragma unroll
    for (int i = 0; i < 4; ++i)
#pragma unroll
      for (int j = 0; j < 4; ++j) acc[i][j] = MFMA16(afe[i][1], bfe[j][1], acc[i][j]);
    __builtin_amdgcn_s_setprio(0);
    if (st) { asm volatile("s_waitcnt vmcnt(4)" ::: "memory"); }
    else    { asm volatile("s_waitcnt vmcnt(0)" ::: "memory"); }
    __builtin_amdgcn_s_barrier();

    // ---- ph2 ----
#pragma unroll
    for (int i = 0; i < 4; ++i) {
      afo[i][0] = *(const bf16x8*)(ao + arow + i * 1024 + c0);
      afo[i][1] = *(const bf16x8*)(ao + arow + i * 1024 + c1);
    }
#pragma unroll
    for (int j = 0; j < 4; ++j)
      bfo[j][0] = *(const bf16x8*)(bo + brow + j * 1024 + c0);
    asm volatile("s_waitcnt lgkmcnt(0)" ::: "memory");
    __builtin_amdgcn_s_barrier();
    if (st) STAGE_BS(0, e + 2);
    __builtin_amdgcn_s_setprio(1);
#pragma unroll
    for (int i = 0; i < 4; ++i)
#pragma unroll
      for (int j = 0; j < 4; ++j) acc[i][j] = MFMA16(afo[i][0], bfo[j][0], acc[i][j]);
    __builtin_amdgcn_s_setprio(0);
    __builtin_amdgcn_s_barrier();

    // ---- ph3 ----
#pragma unroll
    for (int j = 0; j < 4; ++j)
      bfo[j][1] = *(const bf16x8*)(bo + brow + j * 1024 + c1);
    asm volatile("s_waitcnt lgkmcnt(0)" ::: "memory");
    __builtin_amdgcn_s_barrier();
    if (st) { STAGE_A(1, 0, e + 3); STAGE_A(1, 1, e + 3); }
    __builtin_amdgcn_s_setprio(1);
#pragma unroll
    for (int i = 0; i < 4; ++i)
#pragma unroll
      for (int j = 0; j < 4; ++j) acc[i][j] = MFMA16(afo[i][1], bfo[j][1], acc[i][j]);
    __builtin_amdgcn_s_setprio(0);

    if (st) {
      STAGE_BS(1, e + 3);
      asm volatile("s_waitcnt vmcnt(6)" ::: "memory");
      __builtin_amdgcn_s_barrier();
    }
  }

  if constexpr (OUTMODE == 0) {
    __syncthreads();
    bf16* T = &smA[0][0][0];  // [128 f][256 n swizzled] = 64 KiB
#pragma unroll
    for (int i = 0; i < 4; ++i)
#pragma unroll
      for (int r = 0; r < 4; ++r) {
        const int nl = wr * 64 + i * 16 + quad * 4 + r;
#pragma unroll
        for (int j = 0; j < 4; ++j) {
          const int fl = wc * 64 + j * 16 + l15;
          T[fl * 256 + ((((nl >> 3) ^ (fl & 31)) << 3) | (nl & 7))] = (bf16)acc[i][j][r];
        }
      }
    __syncthreads();
    const int f0g = n0, nb0 = m0 & 2047, b = m0 >> 11;
#pragma unroll
    for (int c = 0; c < 8; ++c) {
      const int idx = c * 512 + tid;
      const int fl = idx >> 5, nb = idx & 31;
      bf16x8 o = *(const bf16x8*)(T + fl * 256 + ((nb ^ (fl & 31)) << 3));
      *(bf16x8*)(vt + (size_t)(b * 2048 + f0g + fl) * 2048 + nb0 + nb * 8) = o;
    }
  } else {
#pragma unroll
    for (int i = 0; i < 4; ++i) {
#pragma unroll
      for (int r = 0; r < 4; ++r) {
        const size_t base = (size_t)(m0 + wr * 64 + i * 16 + quad * 4 + r) * 2048
                          + n0 + wc * 64 + l15;
#pragma unroll
        for (int j = 0; j < 4; ++j) C[base + j * 16] = (float)acc[i][j][r];
      }
    }
  }
}

// ---------------- split-K flash attention, causal, S^T ----------------------
// 768 blocks = 32 bh x 24 segments, longest-first. K double-buffered in LDS
// (32 KiB -> 4 blocks/CU, 4 waves/SIMD); V read per-wave directly from
// global (vt rows are contiguous; tile L1-resident for the 3 re-reading
// waves). V-frag issue precedes the K prefetch so the pre-PV vmcnt wait can
// leave the async K loads in flight.
#define SD(qt, kb, ke, sg) ((qt) | ((kb) << 4) | ((ke) << 10) | ((sg) << 16))
__device__ const unsigned seg_desc[24] = {
  SD(7, 0, 16, 2),  SD(15, 0, 16, 0), SD(15, 16, 32, 1),
  SD(14, 0, 15, 0), SD(14, 15, 30, 1),
  SD(6, 0, 14, 2),  SD(13, 0, 14, 0), SD(13, 14, 28, 1),
  SD(12, 0, 13, 0), SD(12, 13, 26, 1),
  SD(5, 0, 12, 2),  SD(11, 0, 12, 0), SD(11, 12, 24, 1),
  SD(10, 0, 11, 0), SD(10, 11, 22, 1),
  SD(4, 0, 10, 2),  SD(9, 0, 10, 0),  SD(9, 10, 20, 1),
  SD(8, 0, 9, 0),   SD(8, 9, 18, 1),
  SD(3, 0, 8, 2),   SD(2, 0, 6, 2),   SD(1, 0, 4, 2),   SD(0, 0, 2, 2)
};

__global__ __launch_bounds__(256, 4)
void attn_kernel(const bf16* __restrict__ qk, const bf16* __restrict__ vt,
                 bf16* __restrict__ yb, float* __restrict__ scratch) {
  constexpr int NSEQ = 2048, E = 2048, QKS = 4096;
  __shared__ __attribute__((aligned(16))) bf16 Ks[2][64 * 128];   // [tok][d], XOR-swizzled
  const int tid = threadIdx.x;
  const int wave = tid >> 6, lane = tid & 63;
  const int l31 = lane & 31, half = lane >> 5;
  const int id = blockIdx.x;
  const int sidx = id >> 5;        // 0..23 (desc-sorted, longest first)
  const int bh = id & 31;
  const unsigned d = seg_desc[sidx];
  const int qt = d & 15;
  const int kbeg = (d >> 4) & 63;
  const int kend = (d >> 10) & 63;
  const int sg = (d >> 16) & 3;    // 0/1 = split segment, 2 = full tile
  const int b = bh >> 4, h = bh & 15;
  const float c1 = 0.08838834764831845f * 1.44269504088896f;  // scale * log2(e)

  const int krow_s = tid >> 4, kch_s = tid & 15;  // K: 16 chunks/row
  const bf16* kg = qk + (size_t)(b * NSEQ) * QKS + 2048 + h * 128;
  const bf16* vg = vt + (size_t)b * E * NSEQ + (size_t)(h * 128) * NSEQ;

  const int diag = 2 * qt + (wave >> 1);

  {  // prefetch K tile kbeg into buffer 0
    bf16* kdst = Ks[0] + tid * 8;
#pragma unroll
    for (int p = 0; p < 4; ++p) {
      int r = p * 16 + krow_s;
      async_load16(kg + (size_t)(kbeg * 64 + r) * QKS + (kch_s ^ (r & 7)) * 8, kdst + p * 2048);
    }
  }

  const int qrow = qt * 128 + wave * 32 + l31;
  bf16x8 qf[8];
  {
    const bf16* qp = qk + (size_t)(b * NSEQ + qrow) * QKS + h * 128 + half * 8;
#pragma unroll
    for (int k8 = 0; k8 < 8; ++k8) qf[k8] = *(const bf16x8*)(qp + k8 * 16);
  }

  float m = -3.0e38f, l = 0.f;
  f32x16 accO[4];
#pragma unroll
  for (int md = 0; md < 4; ++md)
#pragma unroll
    for (int r = 0; r < 16; ++r) accO[md][r] = 0.f;

  union PU { unsigned u; bf16x2 h; };
  union FU { bf16x8 v; unsigned u[4]; };

  const int r31_7 = l31 & 7;  // row&7 for this lane's frag rows

  for (int kt = kbeg; kt < kend; ++kt) {
    const int cur = (kt - kbeg) & 1;
    __syncthreads();

    const bool active = (kt <= diag);

    // ---- V frags direct from global (issued first: newest VMEM ops, so the
    // pre-PV wait keeps the async K loads below in flight) ----
    bf16x8 vf[4][4];
    if (active) {
#pragma unroll
      for (int kk = 0; kk < 4; ++kk)
#pragma unroll
        for (int md = 0; md < 4; ++md) {
          const int row = md * 32 + l31;
          vf[kk][md] = *(const bf16x8*)(vg + (size_t)row * NSEQ + kt * 64
                                        + (kk * 2 + half) * 8);
        }
    }

    if (kt + 1 < kend) {  // prefetch next K tile
      const int nxt = kt + 1;
      bf16* kdst = Ks[1 - cur] + tid * 8;
#pragma unroll
      for (int p = 0; p < 4; ++p) {
        int r = p * 16 + krow_s;
        async_load16(kg + (size_t)(nxt * 64 + r) * QKS + (kch_s ^ (r & 7)) * 8, kdst + p * 2048);
      }
    }

    if (!active) continue;

    const bf16* ks = Ks[cur];

    // ---- batch-load all 16 K-frags from LDS ----
    bf16x8 kf[2][8];
#pragma unroll
    for (int mt = 0; mt < 2; ++mt) {
      const int row = mt * 32 + l31;
#pragma unroll
      for (int k8 = 0; k8 < 8; ++k8)
        kf[mt][k8] = *(const bf16x8*)(ks + row * 128 + (((k8 * 2 + half) ^ r31_7) * 8));
    }

    f32x16 st[2];
#pragma unroll
    for (int mt = 0; mt < 2; ++mt)
#pragma unroll
      for (int r = 0; r < 16; ++r) st[mt][r] = 0.f;
#pragma unroll
    for (int k8 = 0; k8 < 8; ++k8) {
#pragma unroll
      for (int mt = 0; mt < 2; ++mt)
        st[mt] = MFMA32(kf[mt][k8], qf[k8], st[mt]);
    }

    if (kt == diag) {
#pragma unroll
      for (int mt = 0; mt < 2; ++mt)
#pragma unroll
        for (int r = 0; r < 16; ++r) {
          int t = kt * 64 + mt * 32 + (r & 3) + 8 * (r >> 2) + 4 * half;
          if (t > qrow) st[mt][r] = -3.0e38f;
        }
    }

    // ---- online softmax with defer-max (T13) ----
    float mx = -3.0e38f;
#pragma unroll
    for (int mt = 0; mt < 2; ++mt)
#pragma unroll
      for (int r = 0; r < 16; ++r) mx = fmaxf(mx, st[mt][r]);
    mx = fmaxf(mx, __shfl_xor(mx, 32));

    const bool noresc = __all((mx - m) * c1 <= 8.0f);
    const float mnew = noresc ? m : fmaxf(m, mx);
    const float mc = mnew * c1;

    float psum = 0.f;
    unsigned pown[2][4][2];
#pragma unroll
    for (int mt = 0; mt < 2; ++mt)
#pragma unroll
      for (int qd = 0; qd < 4; ++qd)
#pragma unroll
        for (int pr = 0; pr < 2; ++pr) {
          float p0 = exp2f(st[mt][qd * 4 + pr * 2] * c1 - mc);
          float p1 = exp2f(st[mt][qd * 4 + pr * 2 + 1] * c1 - mc);
          psum += p0 + p1;
          PU a; a.h[0] = (bf16)p0; a.h[1] = (bf16)p1;
          pown[mt][qd][pr] = a.u;
        }
    psum += __shfl_xor(psum, 32);

    if (!noresc) {
      const float alpha = exp2f((m - mnew) * c1);
      l *= alpha;
      m = mnew;
#pragma unroll
      for (int md = 0; md < 4; ++md)
#pragma unroll
        for (int r = 0; r < 16; ++r) accO[md][r] *= alpha;
    }
    l += psum;

    // ---- P exchange + PV MFMA (consumes pre-loaded vf) ----
#pragma unroll
    for (int mt = 0; mt < 2; ++mt)
#pragma unroll
      for (int c = 0; c < 2; ++c) {
        const int qa = 2 * c, qb = 2 * c + 1;
        unsigned ra0 = __shfl_xor(pown[mt][qa][0], 32);
        unsigned ra1 = __shfl_xor(pown[mt][qa][1], 32);
        unsigned rb0 = __shfl_xor(pown[mt][qb][0], 32);
        unsigned rb1 = __shfl_xor(pown[mt][qb][1], 32);
        FU f;
        f.u[0] = half ? rb0 : pown[mt][qa][0];
        f.u[1] = half ? rb1 : pown[mt][qa][1];
        f.u[2] = half ? pown[mt][qb][0] : ra0;
        f.u[3] = half ? pown[mt][qb][1] : ra1;
        const int kk = mt * 2 + c;
#pragma unroll
        for (int md = 0; md < 4; ++md)
          accO[md] = MFMA32(vf[kk][md], f.v, accO[md]);
      }
  }

  if (sg == 2) {
    // ---- full segment: normalize + write y ----
    float invl = 1.0f / l;
    bf16* yp = yb + (size_t)(b * NSEQ + qrow) * E + h * 128;
#pragma unroll
    for (int md = 0; md < 4; ++md)
#pragma unroll
      for (int rq = 0; rq < 4; ++rq) {
        bf16x4 o;
#pragma unroll
        for (int i = 0; i < 4; ++i) o[i] = (bf16)(accO[md][rq * 4 + i] * invl);
        *(bf16x4*)(yp + md * 32 + rq * 8 + half * 4) = o;
      }
  } else {
    // ---- partial segment: store (O, m, l) to scratch ----
    const int slot = ((bh * 8 + (qt - 8)) * 2 + sg);
    float* fb = scratch + (size_t)slot * 16640;  // 128*128 O + 128 m + 128 l
    const int row = wave * 32 + l31;
    fb[16384 + row] = m;
    fb[16512 + row] = l;
#pragma unroll
    for (int md = 0; md < 4; ++md)
#pragma unroll
      for (int rq = 0; rq < 4; ++rq) {
        f32x4 o;
#pragma unroll
        for (int i = 0; i < 4; ++i) o[i] = accO[md][rq * 4 + i];
        *(f32x4*)(fb + row * 128 + md * 32 + rq * 8 + half * 4) = o;
      }
  }
}

// ---------------- merge kernel: combine the 2 partials of each qt>=8 tile ---
__global__ __launch_bounds__(256)
void attn_merge_kernel(const float* __restrict__ scratch, bf16* __restrict__ yb) {
  const int blk = blockIdx.x;        // 0..255 = bh*8 + (qt-8)
  const int bh = blk >> 3, qt = (blk & 7) + 8;
  const int b = bh >> 4, h = bh & 15;
  const float* s0 = scratch + (size_t)(blk * 2) * 16640;
  const float* s1 = s0 + 16640;
  const int t = threadIdx.x;
  const int row = t >> 1, d0 = (t & 1) * 64;
  const float c1 = 0.08838834764831845f * 1.44269504088896f;

  const float m0 = s0[16384 + row], l0 = s0[16512 + row];
  const float m1 = s1[16384 + row], l1 = s1[16512 + row];
  const float M = fmaxf(m0, m1);
  float a0 = exp2f((m0 - M) * c1);
  float a1 = exp2f((m1 - M) * c1);
  const float inv = 1.0f / (a0 * l0 + a1 * l1);
  a0 *= inv; a1 *= inv;

  bf16* yp = yb + ((size_t)(b * 2048) + qt * 128 + row) * 2048 + h * 128 + d0;
#pragma unroll
  for (int i = 0; i < 16; ++i) {
    float4 o0 = *(const float4*)(s0 + row * 128 + d0 + i * 4);
    float4 o1 = *(const float4*)(s1 + row * 128 + d0 + i * 4);
    bf16x4 o;
    o[0] = (bf16)(a0 * o0.x + a1 * o1.x);
    o[1] = (bf16)(a0 * o0.y + a1 * o1.y);
    o[2] = (bf16)(a0 * o0.z + a1 * o1.z);
    o[3] = (bf16)(a0 * o0.w + a1 * o1.w);
    *(bf16x4*)(yp + i * 4) = o;
  }
}

// ---------------- launch ----------------
extern "C" void kernel_launch(void* const* d_in, const int* in_sizes, int n_in,
                              void* d_out, int out_size, void* d_ws, size_t ws_size,
                              hipStream_t stream) {
  const float* x    = (const float*)d_in[0];
  const float* Wq   = (const float*)d_in[1];
  const float* Wkv  = (const float*)d_in[2];
  const float* Wout = (const float*)d_in[3];
  float* out = (float*)d_out;

  constexpr size_t NX = (size_t)2 * 2048 * 2048;  // 8388608
  constexpr size_t NW = (size_t)2048 * 2048;      // 4194304

  bf16* xb     = (bf16*)d_ws;
  bf16* wqkvb  = xb + NX;          // [6144 x 2048] = Wq rows then Wkv rows
  bf16* woutb  = wqkvb + 3 * NW;
  bf16* qk_b   = woutb + NW;       // [4096 x 4096]: q | k per row
  bf16* y_b    = qk_b + 2 * NX;
  bf16* vt_b   = y_b + NX;         // [b, f, n] = [2][2048][2048]
  // attn scratch (34.1 MB) aliases xb+wqkvb (41.9 MB) — both dead after the
  // two projection GEMMs, and it ends before woutb (needed by the out-proj).
  float* attn_scr = (float*)d_ws;

  cast_all_kernel<<<12288, 256, 0, stream>>>(x, Wq, Wkv, Wout, xb, wqkvb, woutb);

  // q|k = x @ [Wq; Wk]^T -> qk_b (stride 4096); one exact 256-block round
  gemm_qk_8phase<<<256, 512, 0, stream>>>(xb, wqkvb, qk_b);
  // V = x @ Wv^T -> vt_b transposed; one exact round
  gemm_thin<0><<<256, 512, 0, stream>>>(xb, wqkvb + (size_t)4096 * 2048, vt_b, nullptr);
  // split-K attention -> y (qt<=7 direct) + scratch partials (qt>=8)
  attn_kernel<<<768, 256, 0, stream>>>(qk_b, vt_b, y_b, attn_scr);
  // merge partials -> y rows for qt>=8
  attn_merge_kernel<<<256, 256, 0, stream>>>(attn_scr, y_b);
  // out = y @ Wout^T : fp32; one exact round
  gemm_thin<1><<<256, 512, 0, stream>>>(y_b, woutb, nullptr, out);
}

// Round 9
// 396.436 us; speedup vs baseline: 1.4463x; 1.4463x over previous
//
#include <hip/hip_runtime.h>

// B=2, N=2048, E=2048, H=16, D=128.
// Pipeline: cast fp32->bf16; gemm_qk (256 blocks, 256x256, 4 quadrant-phases,
// T1/T2/T4/T5) -> q|k; gemm_thin<0> (256x128, deepened 4-phase) -> V
// transposed vt[b][f][n]; flash attention (512 blocks, XCD-paired
// complementary qt, K double-buffered 32KB + V single-buffered 16KB = 48KB
// LDS -> 3 blocks/CU, V staged async within-iteration under QK+softmax,
// counted vmcnt); gemm_thin<1> -> out.

typedef __bf16 bf16;
typedef bf16 bf16x2 __attribute__((ext_vector_type(2)));
typedef bf16 bf16x4 __attribute__((ext_vector_type(4)));
typedef bf16 bf16x8 __attribute__((ext_vector_type(8)));
typedef float f32x4 __attribute__((ext_vector_type(4)));
typedef float f32x16 __attribute__((ext_vector_type(16)));

typedef const __attribute__((address_space(1))) void cg_void;
typedef __attribute__((address_space(3))) void lds_void;

#define MFMA16(a, b, c) __builtin_amdgcn_mfma_f32_16x16x32_bf16((a), (b), (c), 0, 0, 0)
#define MFMA32(a, b, c) __builtin_amdgcn_mfma_f32_32x32x16_bf16((a), (b), (c), 0, 0, 0)

__device__ __forceinline__ void async_load16(const bf16* g, bf16* l) {
  __builtin_amdgcn_global_load_lds((cg_void*)g, (lds_void*)l, 16, 0, 0);
}

// ---------------- merged cast fp32 -> bf16 ----------------
__global__ __launch_bounds__(256) void cast_all_kernel(
    const float* __restrict__ x, const float* __restrict__ wq,
    const float* __restrict__ wkv, const float* __restrict__ wout,
    bf16* __restrict__ xb, bf16* __restrict__ wqkvb, bf16* __restrict__ woutb) {
  long i = (long)blockIdx.x * 256 + threadIdx.x;  // 8-elem chunks
  const float* src; bf16* dst; long off;
  if (i < 1048576)      { src = x;    dst = xb;            off = i; }
  else if (i < 2621440) { src = wq;   dst = wqkvb;         off = i - 1048576;
                          if (off >= 524288) { src = wkv; dst = wqkvb + 4194304; off -= 524288; } }
  else                  { src = wout; dst = woutb;         off = i - 2621440; }
  float4 f0 = ((const float4*)src)[2 * off];
  float4 f1 = ((const float4*)src)[2 * off + 1];
  bf16x8 o;
  o[0] = (bf16)f0.x; o[1] = (bf16)f0.y; o[2] = (bf16)f0.z; o[3] = (bf16)f0.w;
  o[4] = (bf16)f1.x; o[5] = (bf16)f1.y; o[6] = (bf16)f1.z; o[7] = (bf16)f1.w;
  ((bf16x8*)dst)[off] = o;
}

// Staging macros (use locals Ag/Bg/ldsA/ldsB). LDS dest is linear
// (global_load_lds writes base+lane*16); the XOR swizzle (16B chunk ^= row&7)
// is pre-applied on the GLOBAL source address.
#define STAGE_A(bufi, h, tt) do {                              \
    const bf16* g_ = Ag + (h) * 262144 + (tt) * 64;            \
    bf16* d_ = ldsA + (bufi) * 16384 + (h) * 8192;             \
    async_load16(g_, d_);                                      \
    async_load16(g_ + 131072, d_ + 4096);                      \
  } while (0)
#define STAGE_B(bufi, h, tt) do {                              \
    const bf16* g_ = Bg + (h) * 262144 + (tt) * 64;            \
    bf16* d_ = ldsB + (bufi) * 16384 + (h) * 8192;             \
    async_load16(g_, d_);                                      \
    async_load16(g_ + 131072, d_ + 4096);                      \
  } while (0)
#define STAGE_BS(bufi, tt) do {                                \
    const bf16* g_ = Bg + (tt) * 64;                           \
    bf16* d_ = ldsB + (bufi) * 8192;                           \
    async_load16(g_, d_);                                      \
    async_load16(g_ + 131072, d_ + 4096);                      \
  } while (0)

// ---------------- q|k GEMM: 256x256 tile, 4 quadrant-phases/K-tile ----------
// (unchanged — control)
__global__ __launch_bounds__(512, 2)
void gemm_qk_8phase(const bf16* __restrict__ A, const bf16* __restrict__ B,
                    bf16* __restrict__ qk) {
  __shared__ __attribute__((aligned(16))) bf16 sm[2][2][256][64];  // 128 KiB
  const int tid = threadIdx.x;
  const int lane = tid & 63;
  const int wid = tid >> 6;
  const int quad = lane >> 4, l15 = lane & 15;
  const int wr = wid >> 2, wc = wid & 3;   // 2M x 4N waves; wave tile 128x64

  const int lb = (blockIdx.x & 7) * 32 + (blockIdx.x >> 3);
  const int bm = lb >> 4, bn = lb & 15;
  const int m0 = bm * 256, n0 = bn * 256;

  const int srow = tid >> 3;
  const int kswz8 = ((tid & 7) ^ (srow & 7)) * 8;
  const bf16* Ag = A + (size_t)(m0 + srow) * 2048 + kswz8;
  const bf16* Bg = B + (size_t)(n0 + srow) * 2048 + kswz8;
  bf16* ldsA = &sm[0][0][0][0] + tid * 8;
  bf16* ldsB = &sm[1][0][0][0] + tid * 8;

  f32x4 acc[8][4];
#pragma unroll
  for (int i = 0; i < 8; ++i)
#pragma unroll
    for (int j = 0; j < 4; ++j) acc[i][j] = {0.f, 0.f, 0.f, 0.f};

  const int r7 = l15 & 7;
  const int c0 = (quad ^ r7) * 8;        // ks=0 swizzled chunk
  const int c1 = ((4 + quad) ^ r7) * 8;  // ks=1
  const int arow = (wr * 128 + l15) * 64;
  const int brow = (wc * 64 + l15) * 64;

  STAGE_A(0, 0, 0); STAGE_A(0, 1, 0); STAGE_B(0, 0, 0); STAGE_B(0, 1, 0);
  STAGE_A(1, 0, 1); STAGE_A(1, 1, 1);
  asm volatile("s_waitcnt vmcnt(4)" ::: "memory");  // tile0 landed
  __builtin_amdgcn_s_barrier();

  for (int t = 0; t < 32; ++t) {
    const int cur = t & 1;
    const bf16* as = &sm[0][0][0][0] + cur * 16384;
    const bf16* bs = &sm[1][0][0][0] + cur * 16384;
    bf16x8 a0[4][2], a1[4][2], b0[2][2], b1[2][2];

    // ---- ph0: q(0,0) ----
#pragma unroll
    for (int i = 0; i < 4; ++i) {
      a0[i][0] = *(const bf16x8*)(as + arow + i * 1024 + c0);
      a0[i][1] = *(const bf16x8*)(as + arow + i * 1024 + c1);
    }
#pragma unroll
    for (int j = 0; j < 2; ++j) {
      b0[j][0] = *(const bf16x8*)(bs + brow + j * 1024 + c0);
      b0[j][1] = *(const bf16x8*)(bs + brow + j * 1024 + c1);
    }
    if (t < 31) STAGE_B(1 - cur, 0, t + 1);
    asm volatile("s_waitcnt lgkmcnt(8)" ::: "memory");
    __builtin_amdgcn_s_barrier();
    asm volatile("s_waitcnt lgkmcnt(0)" ::: "memory");
    __builtin_amdgcn_s_setprio(1);
#pragma unroll
    for (int ks = 0; ks < 2; ++ks)
#pragma unroll
      for (int i = 0; i < 4; ++i)
#pragma unroll
        for (int j = 0; j < 2; ++j) acc[i][j] = MFMA16(a0[i][ks], b0[j][ks], acc[i][j]);
    __builtin_amdgcn_s_setprio(0);
    __builtin_amdgcn_s_barrier();

    // ---- ph1: q(0,1) ----
#pragma unroll
    for (int j = 0; j < 2; ++j) {
      b1[j][0] = *(const bf16x8*)(bs + brow + (2 + j) * 1024 + c0);
      b1[j][1] = *(const bf16x8*)(bs + brow + (2 + j) * 1024 + c1);
    }
    if (t < 31) STAGE_B(1 - cur, 1, t + 1);
    __builtin_amdgcn_s_barrier();
    asm volatile("s_waitcnt lgkmcnt(0)" ::: "memory");
    __builtin_amdgcn_s_setprio(1);
#pragma unroll
    for (int ks = 0; ks < 2; ++ks)
#pragma unroll
      for (int i = 0; i < 4; ++i)
#pragma unroll
        for (int j = 0; j < 2; ++j) acc[i][2 + j] = MFMA16(a0[i][ks], b1[j][ks], acc[i][2 + j]);
    __builtin_amdgcn_s_setprio(0);
    __builtin_amdgcn_s_barrier();

    // ---- ph2: q(1,0) ----
#pragma unroll
    for (int i = 0; i < 4; ++i) {
      a1[i][0] = *(const bf16x8*)(as + arow + (4 + i) * 1024 + c0);
      a1[i][1] = *(const bf16x8*)(as + arow + (4 + i) * 1024 + c1);
    }
    __builtin_amdgcn_s_barrier();
    asm volatile("s_waitcnt lgkmcnt(0)" ::: "memory");
    __builtin_amdgcn_s_setprio(1);
#pragma unroll
    for (int ks = 0; ks < 2; ++ks)
#pragma unroll
      for (int i = 0; i < 4; ++i)
#pragma unroll
        for (int j = 0; j < 2; ++j) acc[4 + i][j] = MFMA16(a1[i][ks], b0[j][ks], acc[4 + i][j]);
    __builtin_amdgcn_s_setprio(0);
    __builtin_amdgcn_s_barrier();

    // ---- ph3: q(1,1) + boundary ----
    __builtin_amdgcn_s_setprio(1);
#pragma unroll
    for (int ks = 0; ks < 2; ++ks)
#pragma unroll
      for (int i = 0; i < 4; ++i)
#pragma unroll
        for (int j = 0; j < 2; ++j) acc[4 + i][2 + j] = MFMA16(a1[i][ks], b1[j][ks], acc[4 + i][2 + j]);
    __builtin_amdgcn_s_setprio(0);
    if (t < 30) {
      STAGE_A(cur, 0, t + 2); STAGE_A(cur, 1, t + 2);
      asm volatile("s_waitcnt vmcnt(4)" ::: "memory");  // t+1 landed
      __builtin_amdgcn_s_barrier();
    } else if (t == 30) {
      asm volatile("s_waitcnt vmcnt(0)" ::: "memory");
      __builtin_amdgcn_s_barrier();
    }
  }

#pragma unroll
  for (int i = 0; i < 8; ++i)
#pragma unroll
    for (int r = 0; r < 4; ++r) {
      const size_t base = (size_t)(m0 + wr * 128 + i * 16 + quad * 4 + r) * 4096
                        + n0 + wc * 64 + l15;
#pragma unroll
      for (int j = 0; j < 4; ++j) qk[base + j * 16] = (bf16)acc[i][j][r];
    }
}

// ---------------- thin GEMM: 256x128, 2-K-tile deepened 4-phase -------------
// (unchanged — control)
template <int OUTMODE>
__global__ __launch_bounds__(512, 2)
void gemm_thin(const bf16* __restrict__ A, const bf16* __restrict__ B,
               bf16* __restrict__ vt, float* __restrict__ C) {
  __shared__ __attribute__((aligned(16))) bf16 smA[2][256][64];  // 64 KiB
  __shared__ __attribute__((aligned(16))) bf16 smB[2][128][64];  // 32 KiB
  const int tid = threadIdx.x;
  const int lane = tid & 63;
  const int wid = tid >> 6;
  const int quad = lane >> 4, l15 = lane & 15;
  const int wr = wid >> 1, wc = wid & 1;   // 4M x 2N waves; wave tile 64x64

  const int lb = (blockIdx.x & 7) * 32 + (blockIdx.x >> 3);
  const int bm = lb >> 4, bn = lb & 15;
  const int m0 = bm * 256, n0 = bn * 128;

  const int srow = tid >> 3;
  const int kswz8 = ((tid & 7) ^ (srow & 7)) * 8;
  const bf16* Ag = A + (size_t)(m0 + srow) * 2048 + kswz8;
  const bf16* Bg = B + (size_t)(n0 + srow) * 2048 + kswz8;
  bf16* ldsA = &smA[0][0][0] + tid * 8;
  bf16* ldsB = &smB[0][0][0] + tid * 8;

  f32x4 acc[4][4];
#pragma unroll
  for (int i = 0; i < 4; ++i)
#pragma unroll
    for (int j = 0; j < 4; ++j) acc[i][j] = {0.f, 0.f, 0.f, 0.f};

  const int r7 = l15 & 7;
  const int c0 = (quad ^ r7) * 8;        // ks=0 swizzled chunk
  const int c1 = ((4 + quad) ^ r7) * 8;  // ks=1
  const int arow = (wr * 64 + l15) * 64;
  const int brow = (wc * 64 + l15) * 64;

  STAGE_A(0, 0, 0); STAGE_A(0, 1, 0); STAGE_BS(0, 0);
  STAGE_A(1, 0, 1); STAGE_A(1, 1, 1); STAGE_BS(1, 1);
  asm volatile("s_waitcnt vmcnt(6)" ::: "memory");
  __builtin_amdgcn_s_barrier();

  const bf16* ae = &smA[0][0][0];
  const bf16* ao = &smA[1][0][0];
  const bf16* be = &smB[0][0][0];
  const bf16* bo = &smB[1][0][0];

  for (int u = 0; u < 16; ++u) {
    const int e = 2 * u;
    const bool st = (u < 15);
    bf16x8 afe[4][2], bfe[4][2], afo[4][2], bfo[4][2];

    // ---- ph0 ----
#pragma unroll
    for (int i = 0; i < 4; ++i) {
      afe[i][0] = *(const bf16x8*)(ae + arow + i * 1024 + c0);
      afe[i][1] = *(const bf16x8*)(ae + arow + i * 1024 + c1);
    }
#pragma unroll
    for (int j = 0; j < 4; ++j)
      bfe[j][0] = *(const bf16x8*)(be + brow + j * 1024 + c0);
    asm volatile("s_waitcnt lgkmcnt(0)" ::: "memory");
    __builtin_amdgcn_s_barrier();
    __builtin_amdgcn_s_setprio(1);
#pragma unroll
    for (int i = 0; i < 4; ++i)
#pragma unroll
      for (int j = 0; j < 4; ++j) acc[i][j] = MFMA16(afe[i][0], bfe[j][0], acc[i][j]);
    __builtin_amdgcn_s_setprio(0);
    __builtin_amdgcn_s_barrier();

    // ---- ph1 ----
#pragma unroll
    for (int j = 0; j < 4; ++j)
      bfe[j][1] = *(const bf16x8*)(be + brow + j * 1024 + c1);
    asm volatile("s_waitcnt lgkmcnt(0)" ::: "memory");
    __builtin_amdgcn_s_barrier();
    if (st) { STAGE_A(0, 0, e + 2); STAGE_A(0, 1, e + 2); }
    __builtin_amdgcn_s_setprio(1);
#pragma unroll
    for (int i = 0; i < 4; ++i)
#pragma unroll
      for (int j = 0; j < 4; ++j) acc[i][j] = MFMA16(afe[i][1], bfe[j][1], acc[i][j]);
    __builtin_amdgcn_s_setprio(0);
    if (st) { asm volatile("s_waitcnt vmcnt(4)" ::: "memory"); }
    else    { asm volatile("s_waitcnt vmcnt(0)" ::: "memory"); }
    __builtin_amdgcn_s_barrier();

    // ---- ph2 ----
#pragma unroll
    for (int i = 0; i < 4; ++i) {
      afo[i][0] = *(const bf16x8*)(ao + arow + i * 1024 + c0);
      afo[i][1] = *(const bf16x8*)(ao + arow + i * 1024 + c1);
    }
#pragma unroll
    for (int j = 0; j < 4; ++j)
      bfo[j][0] = *(const bf16x8*)(bo + brow + j * 1024 + c0);
    asm volatile("s_waitcnt lgkmcnt(0)" ::: "memory");
    __builtin_amdgcn_s_barrier();
    if (st) STAGE_BS(0, e + 2);
    __builtin_amdgcn_s_setprio(1);
#pragma unroll
    for (int i = 0; i < 4; ++i)
#pragma unroll
      for (int j = 0; j < 4; ++j) acc[i][j] = MFMA16(afo[i][0], bfo[j][0], acc[i][j]);
    __builtin_amdgcn_s_setprio(0);
    __builtin_amdgcn_s_barrier();

    // ---- ph3 ----
#pragma unroll
    for (int j = 0; j < 4; ++j)
      bfo[j][1] = *(const bf16x8*)(bo + brow + j * 1024 + c1);
    asm volatile("s_waitcnt lgkmcnt(0)" ::: "memory");
    __builtin_amdgcn_s_barrier();
    if (st) { STAGE_A(1, 0, e + 3); STAGE_A(1, 1, e + 3); }
    __builtin_amdgcn_s_setprio(1);
#pragma unroll
    for (int i = 0; i < 4; ++i)
#pragma unroll
      for (int j = 0; j < 4; ++j) acc[i][j] = MFMA16(afo[i][1], bfo[j][1], acc[i][j]);
    __builtin_amdgcn_s_setprio(0);

    if (st) {
      STAGE_BS(1, e + 3);
      asm volatile("s_waitcnt vmcnt(6)" ::: "memory");
      __builtin_amdgcn_s_barrier();
    }
  }

  if constexpr (OUTMODE == 0) {
    __syncthreads();
    bf16* T = &smA[0][0][0];  // [128 f][256 n swizzled] = 64 KiB
#pragma unroll
    for (int i = 0; i < 4; ++i)
#pragma unroll
      for (int r = 0; r < 4; ++r) {
        const int nl = wr * 64 + i * 16 + quad * 4 + r;
#pragma unroll
        for (int j = 0; j < 4; ++j) {
          const int fl = wc * 64 + j * 16 + l15;
          T[fl * 256 + ((((nl >> 3) ^ (fl & 31)) << 3) | (nl & 7))] = (bf16)acc[i][j][r];
        }
      }
    __syncthreads();
    const int f0g = n0, nb0 = m0 & 2047, b = m0 >> 11;
#pragma unroll
    for (int c = 0; c < 8; ++c) {
      const int idx = c * 512 + tid;
      const int fl = idx >> 5, nb = idx & 31;
      bf16x8 o = *(const bf16x8*)(T + fl * 256 + ((nb ^ (fl & 31)) << 3));
      *(bf16x8*)(vt + (size_t)(b * 2048 + f0g + fl) * 2048 + nb0 + nb * 8) = o;
    }
  } else {
#pragma unroll
    for (int i = 0; i < 4; ++i) {
#pragma unroll
      for (int r = 0; r < 4; ++r) {
        const size_t base = (size_t)(m0 + wr * 64 + i * 16 + quad * 4 + r) * 2048
                          + n0 + wc * 64 + l15;
#pragma unroll
        for (int j = 0; j < 4; ++j) C[base + j * 16] = (float)acc[i][j][r];
      }
    }
  }
}

// ---------------- flash attention, causal, S^T ------------------------------
// 512 blocks, XCD-paired complementary qt (pair sums to 34 iters/CU-pair).
// K double-buffered in LDS (32 KB, global_load_lds prefetch); V SINGLE-
// buffered (16 KB) staged at iteration top and drained by a counted vmcnt(8)
// only after QK+softmax — V load latency hides under compute, K prefetch
// stays in flight across barriers. 48 KB LDS -> 3 blocks/CU (12 waves/CU).
// Per-wave vmcnt ledger: entering each iter = 8 outstanding (K[cur]);
// +8 V -> vmcnt(8) drains K; +8 K-prefetch -> vmcnt(8) drains V.
__global__ __launch_bounds__(256, 3)
void attn_kernel(const bf16* __restrict__ qk, const bf16* __restrict__ vt,
                 bf16* __restrict__ yb) {
  constexpr int NSEQ = 2048, E = 2048, QKS = 4096;
  __shared__ __attribute__((aligned(16))) bf16 Ks[2][64 * 128];  // [tok][d], XOR-swizzled
  __shared__ __attribute__((aligned(16))) bf16 Vs[128 * 64];     // [d][tok], XOR-swizzled
  const int tid = threadIdx.x;
  const int wave = tid >> 6, lane = tid & 63;
  const int l31 = lane & 31, half = lane >> 5;
  const int id = blockIdx.x;
  const int slot = (id >> 5) & 15;
  const int bh = (id & 7) | (((id >> 3) & 3) << 3);
  const int b = bh >> 4, h = bh & 15;
  const int qt = (slot < 8) ? slot : 23 - slot;
  const float c1 = 0.08838834764831845f * 1.44269504088896f;  // scale * log2(e)

  const int krow_s = tid >> 4, kch_s = tid & 15;  // K: 16 chunks/row
  const int vrow_s = tid >> 3, vch_s = tid & 7;   // V: 8 chunks/row
  const bf16* kg = qk + (size_t)(b * NSEQ) * QKS + 2048 + h * 128;
  const bf16* vg = vt + (size_t)b * E * NSEQ + (size_t)(h * 128) * NSEQ;

  const int diag = 2 * qt + (wave >> 1);
  const int ktmax = 2 * qt + 1;

  {  // prologue: K tile 0 -> Ks[0] (8 outstanding entering the loop)
    bf16* kdst = Ks[0] + tid * 8;
#pragma unroll
    for (int p = 0; p < 4; ++p) {
      int r = p * 16 + krow_s;
      async_load16(kg + (size_t)r * QKS + (kch_s ^ (r & 7)) * 8, kdst + p * 2048);
    }
  }

  const int qrow = qt * 128 + wave * 32 + l31;
  bf16x8 qf[8];
  {
    const bf16* qp = qk + (size_t)(b * NSEQ + qrow) * QKS + h * 128 + half * 8;
#pragma unroll
    for (int k8 = 0; k8 < 8; ++k8) qf[k8] = *(const bf16x8*)(qp + k8 * 16);
  }

  float m = -3.0e38f, l = 0.f;
  f32x16 accO[4];
#pragma unroll
  for (int md = 0; md < 4; ++md)
#pragma unroll
    for (int r = 0; r < 16; ++r) accO[md][r] = 0.f;

  union PU { unsigned u; bf16x2 h; };
  union FU { bf16x8 v; unsigned u[4]; };

  const int r31_7 = l31 & 7;  // row&7 for this lane's frag rows

  for (int kt = 0; kt <= ktmax; ++kt) {
    const int cur = kt & 1;

    // ---- V stage for tile kt (single buffer; prev reads done: trailing
    // barrier of last iteration) ----
    {
      bf16* vdst = Vs + tid * 8;
#pragma unroll
      for (int p = 0; p < 4; ++p) {
        int r = p * 32 + vrow_s;
        async_load16(vg + (size_t)r * NSEQ + kt * 64 + (vch_s ^ (r & 7)) * 8, vdst + p * 2048);
      }
    }
    // drain K[cur] (the 8 oldest; V stays in flight; iter0 also drains qf)
    asm volatile("s_waitcnt vmcnt(8)" ::: "memory");
    __builtin_amdgcn_s_barrier();

    const bool active = (kt <= diag);  // wave-uniform

    // ---- QK^T from Ks[cur] ----
    f32x16 st[2];
    if (active) {
      bf16x8 kf[2][8];
#pragma unroll
      for (int mt = 0; mt < 2; ++mt) {
        const int row = mt * 32 + l31;
#pragma unroll
        for (int k8 = 0; k8 < 8; ++k8)
          kf[mt][k8] = *(const bf16x8*)(Ks[cur] + row * 128 + (((k8 * 2 + half) ^ r31_7) * 8));
      }
#pragma unroll
      for (int mt = 0; mt < 2; ++mt)
#pragma unroll
        for (int r = 0; r < 16; ++r) st[mt][r] = 0.f;
#pragma unroll
      for (int k8 = 0; k8 < 8; ++k8)
#pragma unroll
        for (int mt = 0; mt < 2; ++mt)
          st[mt] = MFMA32(kf[mt][k8], qf[k8], st[mt]);
    }

    // ---- K prefetch kt+1 -> Ks[1-cur] (no conflict with Ks[cur] reads) ----
    if (kt < ktmax) {
      bf16* kdst = Ks[1 - cur] + tid * 8;
#pragma unroll
      for (int p = 0; p < 4; ++p) {
        int r = p * 16 + krow_s;
        async_load16(kg + (size_t)((kt + 1) * 64 + r) * QKS + (kch_s ^ (r & 7)) * 8, kdst + p * 2048);
      }
    }

    // ---- softmax with defer-max (T13); V latency hides under this ----
    float psum = 0.f;
    unsigned pown[2][4][2];
    bool noresc = true;
    if (active) {
      if (kt == diag) {
#pragma unroll
        for (int mt = 0; mt < 2; ++mt)
#pragma unroll
          for (int r = 0; r < 16; ++r) {
            int t = kt * 64 + mt * 32 + (r & 3) + 8 * (r >> 2) + 4 * half;
            if (t > qrow) st[mt][r] = -3.0e38f;
          }
      }
      float mx = -3.0e38f;
#pragma unroll
      for (int mt = 0; mt < 2; ++mt)
#pragma unroll
        for (int r = 0; r < 16; ++r) mx = fmaxf(mx, st[mt][r]);
      mx = fmaxf(mx, __shfl_xor(mx, 32));

      noresc = __all((mx - m) * c1 <= 8.0f);
      const float mnew = noresc ? m : fmaxf(m, mx);
      const float mc = mnew * c1;

#pragma unroll
      for (int mt = 0; mt < 2; ++mt)
#pragma unroll
        for (int qd = 0; qd < 4; ++qd)
#pragma unroll
          for (int pr = 0; pr < 2; ++pr) {
            float p0 = exp2f(st[mt][qd * 4 + pr * 2] * c1 - mc);
            float p1 = exp2f(st[mt][qd * 4 + pr * 2 + 1] * c1 - mc);
            psum += p0 + p1;
            PU a; a.h[0] = (bf16)p0; a.h[1] = (bf16)p1;
            pown[mt][qd][pr] = a.u;
          }
      psum += __shfl_xor(psum, 32);

      if (!noresc) {
        const float alpha = exp2f((m - mnew) * c1);
        l *= alpha;
        m = mnew;
#pragma unroll
        for (int md = 0; md < 4; ++md)
#pragma unroll
          for (int r = 0; r < 16; ++r) accO[md][r] *= alpha;
      }
      l += psum;
    }

    // drain V (8 K-prefetch stay in flight; last iter: nothing else -> 0)
    if (kt < ktmax) { asm volatile("s_waitcnt vmcnt(8)" ::: "memory"); }
    else            { asm volatile("s_waitcnt vmcnt(0)" ::: "memory"); }
    __builtin_amdgcn_s_barrier();

    // ---- P exchange + PV MFMA from Vs ----
    if (active) {
#pragma unroll
      for (int mt = 0; mt < 2; ++mt)
#pragma unroll
        for (int c = 0; c < 2; ++c) {
          const int qa = 2 * c, qb = 2 * c + 1;
          unsigned ra0 = __shfl_xor(pown[mt][qa][0], 32);
          unsigned ra1 = __shfl_xor(pown[mt][qa][1], 32);
          unsigned rb0 = __shfl_xor(pown[mt][qb][0], 32);
          unsigned rb1 = __shfl_xor(pown[mt][qb][1], 32);
          FU f;
          f.u[0] = half ? rb0 : pown[mt][qa][0];
          f.u[1] = half ? rb1 : pown[mt][qa][1];
          f.u[2] = half ? pown[mt][qb][0] : ra0;
          f.u[3] = half ? pown[mt][qb][1] : ra1;
          const int kk = mt * 2 + c;
#pragma unroll
          for (int md = 0; md < 4; ++md) {
            const int row = md * 32 + l31;
            bf16x8 vf = *(const bf16x8*)(Vs + row * 64 + (((kk * 2 + half) ^ (row & 7)) * 8));
            accO[md] = MFMA32(vf, f.v, accO[md]);
          }
        }
    }
    __builtin_amdgcn_s_barrier();  // Vs reads retired before next overwrite
  }

  float invl = 1.0f / l;
  bf16* yp = yb + (size_t)(b * NSEQ + qrow) * E + h * 128;
#pragma unroll
  for (int md = 0; md < 4; ++md)
#pragma unroll
    for (int rq = 0; rq < 4; ++rq) {
      bf16x4 o;
#pragma unroll
      for (int i = 0; i < 4; ++i) o[i] = (bf16)(accO[md][rq * 4 + i] * invl);
      *(bf16x4*)(yp + md * 32 + rq * 8 + half * 4) = o;
    }
}

// ---------------- launch ----------------
extern "C" void kernel_launch(void* const* d_in, const int* in_sizes, int n_in,
                              void* d_out, int out_size, void* d_ws, size_t ws_size,
                              hipStream_t stream) {
  const float* x    = (const float*)d_in[0];
  const float* Wq   = (const float*)d_in[1];
  const float* Wkv  = (const float*)d_in[2];
  const float* Wout = (const float*)d_in[3];
  float* out = (float*)d_out;

  constexpr size_t NX = (size_t)2 * 2048 * 2048;  // 8388608
  constexpr size_t NW = (size_t)2048 * 2048;      // 4194304

  bf16* xb     = (bf16*)d_ws;
  bf16* wqkvb  = xb + NX;          // [6144 x 2048] = Wq rows then Wkv rows
  bf16* woutb  = wqkvb + 3 * NW;
  bf16* qk_b   = woutb + NW;       // [4096 x 4096]: q | k per row
  bf16* y_b    = qk_b + 2 * NX;
  bf16* vt_b   = y_b + NX;         // [b, f, n] = [2][2048][2048]

  cast_all_kernel<<<12288, 256, 0, stream>>>(x, Wq, Wkv, Wout, xb, wqkvb, woutb);

  // q|k = x @ [Wq; Wk]^T -> qk_b (stride 4096); one exact 256-block round
  gemm_qk_8phase<<<256, 512, 0, stream>>>(xb, wqkvb, qk_b);
  // V = x @ Wv^T -> vt_b transposed; one exact round
  gemm_thin<0><<<256, 512, 0, stream>>>(xb, wqkvb + (size_t)4096 * 2048, vt_b, nullptr);
  // attention -> y [4096, 2048] bf16
  attn_kernel<<<512, 256, 0, stream>>>(qk_b, vt_b, y_b);
  // out = y @ Wout^T : fp32; one exact round
  gemm_thin<1><<<256, 512, 0, stream>>>(y_b, woutb, nullptr, out);
}

// Round 10
// 343.141 us; speedup vs baseline: 1.6710x; 1.1553x over previous
//
#include <hip/hip_runtime.h>

// B=2, N=2048, E=2048, H=16, D=128.
// Pipeline: cast fp32->bf16; gemm_qk (256 blocks, 256x256, 4 quadrant-phases,
// T1/T2/T4/T5) -> q|k; gemm_thin<0> (256x128, deepened 4-phase) -> V
// transposed vt[b][f][n]; flash attention (512 blocks, XCD-paired
// complementary qt, K+V double-buffered 64KB LDS, defer-max, batched frag
// reads, K-tile 16-slot XOR swizzle -> 2-way/free bank access);
// gemm_thin<1> -> out.

typedef __bf16 bf16;
typedef bf16 bf16x2 __attribute__((ext_vector_type(2)));
typedef bf16 bf16x4 __attribute__((ext_vector_type(4)));
typedef bf16 bf16x8 __attribute__((ext_vector_type(8)));
typedef float f32x4 __attribute__((ext_vector_type(4)));
typedef float f32x16 __attribute__((ext_vector_type(16)));

typedef const __attribute__((address_space(1))) void cg_void;
typedef __attribute__((address_space(3))) void lds_void;

#define MFMA16(a, b, c) __builtin_amdgcn_mfma_f32_16x16x32_bf16((a), (b), (c), 0, 0, 0)
#define MFMA32(a, b, c) __builtin_amdgcn_mfma_f32_32x32x16_bf16((a), (b), (c), 0, 0, 0)

__device__ __forceinline__ void async_load16(const bf16* g, bf16* l) {
  __builtin_amdgcn_global_load_lds((cg_void*)g, (lds_void*)l, 16, 0, 0);
}

// ---------------- merged cast fp32 -> bf16 ----------------
__global__ __launch_bounds__(256) void cast_all_kernel(
    const float* __restrict__ x, const float* __restrict__ wq,
    const float* __restrict__ wkv, const float* __restrict__ wout,
    bf16* __restrict__ xb, bf16* __restrict__ wqkvb, bf16* __restrict__ woutb) {
  long i = (long)blockIdx.x * 256 + threadIdx.x;  // 8-elem chunks
  const float* src; bf16* dst; long off;
  if (i < 1048576)      { src = x;    dst = xb;            off = i; }
  else if (i < 2621440) { src = wq;   dst = wqkvb;         off = i - 1048576;
                          if (off >= 524288) { src = wkv; dst = wqkvb + 4194304; off -= 524288; } }
  else                  { src = wout; dst = woutb;         off = i - 2621440; }
  float4 f0 = ((const float4*)src)[2 * off];
  float4 f1 = ((const float4*)src)[2 * off + 1];
  bf16x8 o;
  o[0] = (bf16)f0.x; o[1] = (bf16)f0.y; o[2] = (bf16)f0.z; o[3] = (bf16)f0.w;
  o[4] = (bf16)f1.x; o[5] = (bf16)f1.y; o[6] = (bf16)f1.z; o[7] = (bf16)f1.w;
  ((bf16x8*)dst)[off] = o;
}

// Staging macros (use locals Ag/Bg/ldsA/ldsB). LDS dest is linear
// (global_load_lds writes base+lane*16); the XOR swizzle (16B chunk ^= row&7)
// is pre-applied on the GLOBAL source address.
#define STAGE_A(bufi, h, tt) do {                              \
    const bf16* g_ = Ag + (h) * 262144 + (tt) * 64;            \
    bf16* d_ = ldsA + (bufi) * 16384 + (h) * 8192;             \
    async_load16(g_, d_);                                      \
    async_load16(g_ + 131072, d_ + 4096);                      \
  } while (0)
#define STAGE_B(bufi, h, tt) do {                              \
    const bf16* g_ = Bg + (h) * 262144 + (tt) * 64;            \
    bf16* d_ = ldsB + (bufi) * 16384 + (h) * 8192;             \
    async_load16(g_, d_);                                      \
    async_load16(g_ + 131072, d_ + 4096);                      \
  } while (0)
#define STAGE_BS(bufi, tt) do {                                \
    const bf16* g_ = Bg + (tt) * 64;                           \
    bf16* d_ = ldsB + (bufi) * 8192;                           \
    async_load16(g_, d_);                                      \
    async_load16(g_ + 131072, d_ + 4096);                      \
  } while (0)

// ---------------- q|k GEMM: 256x256 tile, 4 quadrant-phases/K-tile ----------
// (unchanged — control)
__global__ __launch_bounds__(512, 2)
void gemm_qk_8phase(const bf16* __restrict__ A, const bf16* __restrict__ B,
                    bf16* __restrict__ qk) {
  __shared__ __attribute__((aligned(16))) bf16 sm[2][2][256][64];  // 128 KiB
  const int tid = threadIdx.x;
  const int lane = tid & 63;
  const int wid = tid >> 6;
  const int quad = lane >> 4, l15 = lane & 15;
  const int wr = wid >> 2, wc = wid & 3;   // 2M x 4N waves; wave tile 128x64

  const int lb = (blockIdx.x & 7) * 32 + (blockIdx.x >> 3);
  const int bm = lb >> 4, bn = lb & 15;
  const int m0 = bm * 256, n0 = bn * 256;

  const int srow = tid >> 3;
  const int kswz8 = ((tid & 7) ^ (srow & 7)) * 8;
  const bf16* Ag = A + (size_t)(m0 + srow) * 2048 + kswz8;
  const bf16* Bg = B + (size_t)(n0 + srow) * 2048 + kswz8;
  bf16* ldsA = &sm[0][0][0][0] + tid * 8;
  bf16* ldsB = &sm[1][0][0][0] + tid * 8;

  f32x4 acc[8][4];
#pragma unroll
  for (int i = 0; i < 8; ++i)
#pragma unroll
    for (int j = 0; j < 4; ++j) acc[i][j] = {0.f, 0.f, 0.f, 0.f};

  const int r7 = l15 & 7;
  const int c0 = (quad ^ r7) * 8;        // ks=0 swizzled chunk
  const int c1 = ((4 + quad) ^ r7) * 8;  // ks=1
  const int arow = (wr * 128 + l15) * 64;
  const int brow = (wc * 64 + l15) * 64;

  STAGE_A(0, 0, 0); STAGE_A(0, 1, 0); STAGE_B(0, 0, 0); STAGE_B(0, 1, 0);
  STAGE_A(1, 0, 1); STAGE_A(1, 1, 1);
  asm volatile("s_waitcnt vmcnt(4)" ::: "memory");  // tile0 landed
  __builtin_amdgcn_s_barrier();

  for (int t = 0; t < 32; ++t) {
    const int cur = t & 1;
    const bf16* as = &sm[0][0][0][0] + cur * 16384;
    const bf16* bs = &sm[1][0][0][0] + cur * 16384;
    bf16x8 a0[4][2], a1[4][2], b0[2][2], b1[2][2];

    // ---- ph0: q(0,0) ----
#pragma unroll
    for (int i = 0; i < 4; ++i) {
      a0[i][0] = *(const bf16x8*)(as + arow + i * 1024 + c0);
      a0[i][1] = *(const bf16x8*)(as + arow + i * 1024 + c1);
    }
#pragma unroll
    for (int j = 0; j < 2; ++j) {
      b0[j][0] = *(const bf16x8*)(bs + brow + j * 1024 + c0);
      b0[j][1] = *(const bf16x8*)(bs + brow + j * 1024 + c1);
    }
    if (t < 31) STAGE_B(1 - cur, 0, t + 1);
    asm volatile("s_waitcnt lgkmcnt(8)" ::: "memory");
    __builtin_amdgcn_s_barrier();
    asm volatile("s_waitcnt lgkmcnt(0)" ::: "memory");
    __builtin_amdgcn_s_setprio(1);
#pragma unroll
    for (int ks = 0; ks < 2; ++ks)
#pragma unroll
      for (int i = 0; i < 4; ++i)
#pragma unroll
        for (int j = 0; j < 2; ++j) acc[i][j] = MFMA16(a0[i][ks], b0[j][ks], acc[i][j]);
    __builtin_amdgcn_s_setprio(0);
    __builtin_amdgcn_s_barrier();

    // ---- ph1: q(0,1) ----
#pragma unroll
    for (int j = 0; j < 2; ++j) {
      b1[j][0] = *(const bf16x8*)(bs + brow + (2 + j) * 1024 + c0);
      b1[j][1] = *(const bf16x8*)(bs + brow + (2 + j) * 1024 + c1);
    }
    if (t < 31) STAGE_B(1 - cur, 1, t + 1);
    __builtin_amdgcn_s_barrier();
    asm volatile("s_waitcnt lgkmcnt(0)" ::: "memory");
    __builtin_amdgcn_s_setprio(1);
#pragma unroll
    for (int ks = 0; ks < 2; ++ks)
#pragma unroll
      for (int i = 0; i < 4; ++i)
#pragma unroll
        for (int j = 0; j < 2; ++j) acc[i][2 + j] = MFMA16(a0[i][ks], b1[j][ks], acc[i][2 + j]);
    __builtin_amdgcn_s_setprio(0);
    __builtin_amdgcn_s_barrier();

    // ---- ph2: q(1,0) ----
#pragma unroll
    for (int i = 0; i < 4; ++i) {
      a1[i][0] = *(const bf16x8*)(as + arow + (4 + i) * 1024 + c0);
      a1[i][1] = *(const bf16x8*)(as + arow + (4 + i) * 1024 + c1);
    }
    __builtin_amdgcn_s_barrier();
    asm volatile("s_waitcnt lgkmcnt(0)" ::: "memory");
    __builtin_amdgcn_s_setprio(1);
#pragma unroll
    for (int ks = 0; ks < 2; ++ks)
#pragma unroll
      for (int i = 0; i < 4; ++i)
#pragma unroll
        for (int j = 0; j < 2; ++j) acc[4 + i][j] = MFMA16(a1[i][ks], b0[j][ks], acc[4 + i][j]);
    __builtin_amdgcn_s_setprio(0);
    __builtin_amdgcn_s_barrier();

    // ---- ph3: q(1,1) + boundary ----
    __builtin_amdgcn_s_setprio(1);
#pragma unroll
    for (int ks = 0; ks < 2; ++ks)
#pragma unroll
      for (int i = 0; i < 4; ++i)
#pragma unroll
        for (int j = 0; j < 2; ++j) acc[4 + i][2 + j] = MFMA16(a1[i][ks], b1[j][ks], acc[4 + i][2 + j]);
    __builtin_amdgcn_s_setprio(0);
    if (t < 30) {
      STAGE_A(cur, 0, t + 2); STAGE_A(cur, 1, t + 2);
      asm volatile("s_waitcnt vmcnt(4)" ::: "memory");  // t+1 landed
      __builtin_amdgcn_s_barrier();
    } else if (t == 30) {
      asm volatile("s_waitcnt vmcnt(0)" ::: "memory");
      __builtin_amdgcn_s_barrier();
    }
  }

#pragma unroll
  for (int i = 0; i < 8; ++i)
#pragma unroll
    for (int r = 0; r < 4; ++r) {
      const size_t base = (size_t)(m0 + wr * 128 + i * 16 + quad * 4 + r) * 4096
                        + n0 + wc * 64 + l15;
#pragma unroll
      for (int j = 0; j < 4; ++j) qk[base + j * 16] = (bf16)acc[i][j][r];
    }
}

// ---------------- thin GEMM: 256x128, 2-K-tile deepened 4-phase -------------
// (unchanged — control)
template <int OUTMODE>
__global__ __launch_bounds__(512, 2)
void gemm_thin(const bf16* __restrict__ A, const bf16* __restrict__ B,
               bf16* __restrict__ vt, float* __restrict__ C) {
  __shared__ __attribute__((aligned(16))) bf16 smA[2][256][64];  // 64 KiB
  __shared__ __attribute__((aligned(16))) bf16 smB[2][128][64];  // 32 KiB
  const int tid = threadIdx.x;
  const int lane = tid & 63;
  const int wid = tid >> 6;
  const int quad = lane >> 4, l15 = lane & 15;
  const int wr = wid >> 1, wc = wid & 1;   // 4M x 2N waves; wave tile 64x64

  const int lb = (blockIdx.x & 7) * 32 + (blockIdx.x >> 3);
  const int bm = lb >> 4, bn = lb & 15;
  const int m0 = bm * 256, n0 = bn * 128;

  const int srow = tid >> 3;
  const int kswz8 = ((tid & 7) ^ (srow & 7)) * 8;
  const bf16* Ag = A + (size_t)(m0 + srow) * 2048 + kswz8;
  const bf16* Bg = B + (size_t)(n0 + srow) * 2048 + kswz8;
  bf16* ldsA = &smA[0][0][0] + tid * 8;
  bf16* ldsB = &smB[0][0][0] + tid * 8;

  f32x4 acc[4][4];
#pragma unroll
  for (int i = 0; i < 4; ++i)
#pragma unroll
    for (int j = 0; j < 4; ++j) acc[i][j] = {0.f, 0.f, 0.f, 0.f};

  const int r7 = l15 & 7;
  const int c0 = (quad ^ r7) * 8;        // ks=0 swizzled chunk
  const int c1 = ((4 + quad) ^ r7) * 8;  // ks=1
  const int arow = (wr * 64 + l15) * 64;
  const int brow = (wc * 64 + l15) * 64;

  STAGE_A(0, 0, 0); STAGE_A(0, 1, 0); STAGE_BS(0, 0);
  STAGE_A(1, 0, 1); STAGE_A(1, 1, 1); STAGE_BS(1, 1);
  asm volatile("s_waitcnt vmcnt(6)" ::: "memory");
  __builtin_amdgcn_s_barrier();

  const bf16* ae = &smA[0][0][0];
  const bf16* ao = &smA[1][0][0];
  const bf16* be = &smB[0][0][0];
  const bf16* bo = &smB[1][0][0];

  for (int u = 0; u < 16; ++u) {
    const int e = 2 * u;
    const bool st = (u < 15);
    bf16x8 afe[4][2], bfe[4][2], afo[4][2], bfo[4][2];

    // ---- ph0 ----
#pragma unroll
    for (int i = 0; i < 4; ++i) {
      afe[i][0] = *(const bf16x8*)(ae + arow + i * 1024 + c0);
      afe[i][1] = *(const bf16x8*)(ae + arow + i * 1024 + c1);
    }
#pragma unroll
    for (int j = 0; j < 4; ++j)
      bfe[j][0] = *(const bf16x8*)(be + brow + j * 1024 + c0);
    asm volatile("s_waitcnt lgkmcnt(0)" ::: "memory");
    __builtin_amdgcn_s_barrier();
    __builtin_amdgcn_s_setprio(1);
#pragma unroll
    for (int i = 0; i < 4; ++i)
#pragma unroll
      for (int j = 0; j < 4; ++j) acc[i][j] = MFMA16(afe[i][0], bfe[j][0], acc[i][j]);
    __builtin_amdgcn_s_setprio(0);
    __builtin_amdgcn_s_barrier();

    // ---- ph1 ----
#pragma unroll
    for (int j = 0; j < 4; ++j)
      bfe[j][1] = *(const bf16x8*)(be + brow + j * 1024 + c1);
    asm volatile("s_waitcnt lgkmcnt(0)" ::: "memory");
    __builtin_amdgcn_s_barrier();
    if (st) { STAGE_A(0, 0, e + 2); STAGE_A(0, 1, e + 2); }
    __builtin_amdgcn_s_setprio(1);
#pragma unroll
    for (int i = 0; i < 4; ++i)
#pragma unroll
      for (int j = 0; j < 4; ++j) acc[i][j] = MFMA16(afe[i][1], bfe[j][1], acc[i][j]);
    __builtin_amdgcn_s_setprio(0);
    if (st) { asm volatile("s_waitcnt vmcnt(4)" ::: "memory"); }
    else    { asm volatile("s_waitcnt vmcnt(0)" ::: "memory"); }
    __builtin_amdgcn_s_barrier();

    // ---- ph2 ----
#pragma unroll
    for (int i = 0; i < 4; ++i) {
      afo[i][0] = *(const bf16x8*)(ao + arow + i * 1024 + c0);
      afo[i][1] = *(const bf16x8*)(ao + arow + i * 1024 + c1);
    }
#pragma unroll
    for (int j = 0; j < 4; ++j)
      bfo[j][0] = *(const bf16x8*)(bo + brow + j * 1024 + c0);
    asm volatile("s_waitcnt lgkmcnt(0)" ::: "memory");
    __builtin_amdgcn_s_barrier();
    if (st) STAGE_BS(0, e + 2);
    __builtin_amdgcn_s_setprio(1);
#pragma unroll
    for (int i = 0; i < 4; ++i)
#pragma unroll
      for (int j = 0; j < 4; ++j) acc[i][j] = MFMA16(afo[i][0], bfo[j][0], acc[i][j]);
    __builtin_amdgcn_s_setprio(0);
    __builtin_amdgcn_s_barrier();

    // ---- ph3 ----
#pragma unroll
    for (int j = 0; j < 4; ++j)
      bfo[j][1] = *(const bf16x8*)(bo + brow + j * 1024 + c1);
    asm volatile("s_waitcnt lgkmcnt(0)" ::: "memory");
    __builtin_amdgcn_s_barrier();
    if (st) { STAGE_A(1, 0, e + 3); STAGE_A(1, 1, e + 3); }
    __builtin_amdgcn_s_setprio(1);
#pragma unroll
    for (int i = 0; i < 4; ++i)
#pragma unroll
      for (int j = 0; j < 4; ++j) acc[i][j] = MFMA16(afo[i][1], bfo[j][1], acc[i][j]);
    __builtin_amdgcn_s_setprio(0);

    if (st) {
      STAGE_BS(1, e + 3);
      asm volatile("s_waitcnt vmcnt(6)" ::: "memory");
      __builtin_amdgcn_s_barrier();
    }
  }

  if constexpr (OUTMODE == 0) {
    __syncthreads();
    bf16* T = &smA[0][0][0];  // [128 f][256 n swizzled] = 64 KiB
#pragma unroll
    for (int i = 0; i < 4; ++i)
#pragma unroll
      for (int r = 0; r < 4; ++r) {
        const int nl = wr * 64 + i * 16 + quad * 4 + r;
#pragma unroll
        for (int j = 0; j < 4; ++j) {
          const int fl = wc * 64 + j * 16 + l15;
          T[fl * 256 + ((((nl >> 3) ^ (fl & 31)) << 3) | (nl & 7))] = (bf16)acc[i][j][r];
        }
      }
    __syncthreads();
    const int f0g = n0, nb0 = m0 & 2047, b = m0 >> 11;
#pragma unroll
    for (int c = 0; c < 8; ++c) {
      const int idx = c * 512 + tid;
      const int fl = idx >> 5, nb = idx & 31;
      bf16x8 o = *(const bf16x8*)(T + fl * 256 + ((nb ^ (fl & 31)) << 3));
      *(bf16x8*)(vt + (size_t)(b * 2048 + f0g + fl) * 2048 + nb0 + nb * 8) = o;
    }
  } else {
#pragma unroll
    for (int i = 0; i < 4; ++i) {
#pragma unroll
      for (int r = 0; r < 4; ++r) {
        const size_t base = (size_t)(m0 + wr * 64 + i * 16 + quad * 4 + r) * 2048
                          + n0 + wc * 64 + l15;
#pragma unroll
        for (int j = 0; j < 4; ++j) C[base + j * 16] = (float)acc[i][j][r];
      }
    }
  }
}

// ---------------- flash attention, causal, S^T, double-buffered --------------
// R6 structure (best measured: K+V double-buffered, one barrier/iter, batched
// frag reads, defer-max) + K-tile 16-slot XOR swizzle: K rows are 128 bf16 =
// 16 chunks, so `chunk ^= row&15` spreads 32 rows over 16 bank-slots -> 2-way
// (free, m136) instead of the 8-slot swizzle's 4-way. Applied on BOTH sides
// (staging global-source pre-swizzle and frag read). V rows have only 8
// chunks; keeps &7.
__global__ __launch_bounds__(256, 2)
void attn_kernel(const bf16* __restrict__ qk, const bf16* __restrict__ vt,
                 bf16* __restrict__ yb) {
  constexpr int NSEQ = 2048, E = 2048, QKS = 4096;
  __shared__ __attribute__((aligned(16))) bf16 Ks[2][64 * 128];   // [tok][d], XOR-swizzled (16-slot)
  __shared__ __attribute__((aligned(16))) bf16 Vs[2][128 * 64];   // [d][tok], XOR-swizzled (8-slot)
  const int tid = threadIdx.x;
  const int wave = tid >> 6, lane = tid & 63;
  const int l31 = lane & 31, half = lane >> 5;
  const int id = blockIdx.x;
  const int slot = (id >> 5) & 15;
  const int bh = (id & 7) | (((id >> 3) & 3) << 3);
  const int b = bh >> 4, h = bh & 15;
  const int qt = (slot < 8) ? slot : 23 - slot;
  const float c1 = 0.08838834764831845f * 1.44269504088896f;  // scale * log2(e)

  const int krow_s = tid >> 4, kch_s = tid & 15;  // K: 16 chunks/row
  const int vrow_s = tid >> 3, vch_s = tid & 7;   // V: 8 chunks/row
  const bf16* kg = qk + (size_t)(b * NSEQ) * QKS + 2048 + h * 128;
  const bf16* vg = vt + (size_t)b * E * NSEQ + (size_t)(h * 128) * NSEQ;

  const int diag = 2 * qt + (wave >> 1);
  const int ktmax = 2 * qt + 1;

  {
    bf16* kdst = Ks[0] + tid * 8;
    bf16* vdst = Vs[0] + tid * 8;
#pragma unroll
    for (int p = 0; p < 4; ++p) {
      int r = p * 16 + krow_s;
      async_load16(kg + (size_t)r * QKS + (kch_s ^ (r & 15)) * 8, kdst + p * 2048);
    }
#pragma unroll
    for (int p = 0; p < 4; ++p) {
      int r = p * 32 + vrow_s;
      async_load16(vg + (size_t)r * NSEQ + (vch_s ^ (r & 7)) * 8, vdst + p * 2048);
    }
  }

  const int qrow = qt * 128 + wave * 32 + l31;
  bf16x8 qf[8];
  {
    const bf16* qp = qk + (size_t)(b * NSEQ + qrow) * QKS + h * 128 + half * 8;
#pragma unroll
    for (int k8 = 0; k8 < 8; ++k8) qf[k8] = *(const bf16x8*)(qp + k8 * 16);
  }

  float m = -3.0e38f, l = 0.f;
  f32x16 accO[4];
#pragma unroll
  for (int md = 0; md < 4; ++md)
#pragma unroll
    for (int r = 0; r < 16; ++r) accO[md][r] = 0.f;

  union PU { unsigned u; bf16x2 h; };
  union FU { bf16x8 v; unsigned u[4]; };

  const int r31_7 = l31 & 7;    // row&7 for V frag rows
  const int r31_15 = l31 & 15;  // row&15 for K frag rows

  for (int kt = 0; kt <= ktmax; ++kt) {
    const int cur = kt & 1;
    __syncthreads();

    if (kt < ktmax) {
      const int nxt = kt + 1;
      bf16* kdst = Ks[1 - cur] + tid * 8;
      bf16* vdst = Vs[1 - cur] + tid * 8;
#pragma unroll
      for (int p = 0; p < 4; ++p) {
        int r = p * 16 + krow_s;
        async_load16(kg + (size_t)(nxt * 64 + r) * QKS + (kch_s ^ (r & 15)) * 8, kdst + p * 2048);
      }
#pragma unroll
      for (int p = 0; p < 4; ++p) {
        int r = p * 32 + vrow_s;
        async_load16(vg + (size_t)r * NSEQ + nxt * 64 + (vch_s ^ (r & 7)) * 8, vdst + p * 2048);
      }
    }

    if (kt > diag) continue;

    const bf16* ks = Ks[cur];
    const bf16* vs = Vs[cur];

    // ---- batch-load all 16 K-frags (independent b128 reads pipeline) ----
    bf16x8 kf[2][8];
#pragma unroll
    for (int mt = 0; mt < 2; ++mt) {
      const int row = mt * 32 + l31;
#pragma unroll
      for (int k8 = 0; k8 < 8; ++k8)
        kf[mt][k8] = *(const bf16x8*)(ks + row * 128 + (((k8 * 2 + half) ^ r31_15) * 8));
    }

    f32x16 st[2];
#pragma unroll
    for (int mt = 0; mt < 2; ++mt)
#pragma unroll
      for (int r = 0; r < 16; ++r) st[mt][r] = 0.f;
#pragma unroll
    for (int k8 = 0; k8 < 8; ++k8) {
#pragma unroll
      for (int mt = 0; mt < 2; ++mt)
        st[mt] = MFMA32(kf[mt][k8], qf[k8], st[mt]);
    }

    // ---- issue all 16 V-frag reads NOW; latency hides under softmax ----
    bf16x8 vf[4][4];
#pragma unroll
    for (int kk = 0; kk < 4; ++kk)
#pragma unroll
      for (int md = 0; md < 4; ++md) {
        const int row = md * 32 + l31;
        vf[kk][md] = *(const bf16x8*)(vs + row * 64 + (((kk * 2 + half) ^ r31_7) * 8));
      }

    if (kt == diag) {
#pragma unroll
      for (int mt = 0; mt < 2; ++mt)
#pragma unroll
        for (int r = 0; r < 16; ++r) {
          int t = kt * 64 + mt * 32 + (r & 3) + 8 * (r >> 2) + 4 * half;
          if (t > qrow) st[mt][r] = -3.0e38f;
        }
    }

    // ---- online softmax with defer-max (T13) ----
    float mx = -3.0e38f;
#pragma unroll
    for (int mt = 0; mt < 2; ++mt)
#pragma unroll
      for (int r = 0; r < 16; ++r) mx = fmaxf(mx, st[mt][r]);
    mx = fmaxf(mx, __shfl_xor(mx, 32));

    const bool noresc = __all((mx - m) * c1 <= 8.0f);
    const float mnew = noresc ? m : fmaxf(m, mx);
    const float mc = mnew * c1;

    float psum = 0.f;
    unsigned pown[2][4][2];
#pragma unroll
    for (int mt = 0; mt < 2; ++mt)
#pragma unroll
      for (int qd = 0; qd < 4; ++qd)
#pragma unroll
        for (int pr = 0; pr < 2; ++pr) {
          float p0 = exp2f(st[mt][qd * 4 + pr * 2] * c1 - mc);
          float p1 = exp2f(st[mt][qd * 4 + pr * 2 + 1] * c1 - mc);
          psum += p0 + p1;
          PU a; a.h[0] = (bf16)p0; a.h[1] = (bf16)p1;
          pown[mt][qd][pr] = a.u;
        }
    psum += __shfl_xor(psum, 32);

    if (!noresc) {
      const float alpha = exp2f((m - mnew) * c1);
      l *= alpha;
      m = mnew;
#pragma unroll
      for (int md = 0; md < 4; ++md)
#pragma unroll
        for (int r = 0; r < 16; ++r) accO[md][r] *= alpha;
    }
    l += psum;

    // ---- P exchange + PV MFMA (consumes pre-loaded vf) ----
#pragma unroll
    for (int mt = 0; mt < 2; ++mt)
#pragma unroll
      for (int c = 0; c < 2; ++c) {
        const int qa = 2 * c, qb = 2 * c + 1;
        unsigned ra0 = __shfl_xor(pown[mt][qa][0], 32);
        unsigned ra1 = __shfl_xor(pown[mt][qa][1], 32);
        unsigned rb0 = __shfl_xor(pown[mt][qb][0], 32);
        unsigned rb1 = __shfl_xor(pown[mt][qb][1], 32);
        FU f;
        f.u[0] = half ? rb0 : pown[mt][qa][0];
        f.u[1] = half ? rb1 : pown[mt][qa][1];
        f.u[2] = half ? pown[mt][qb][0] : ra0;
        f.u[3] = half ? pown[mt][qb][1] : ra1;
        const int kk = mt * 2 + c;
#pragma unroll
        for (int md = 0; md < 4; ++md)
          accO[md] = MFMA32(vf[kk][md], f.v, accO[md]);
      }
  }

  float invl = 1.0f / l;
  bf16* yp = yb + (size_t)(b * NSEQ + qrow) * E + h * 128;
#pragma unroll
  for (int md = 0; md < 4; ++md)
#pragma unroll
    for (int rq = 0; rq < 4; ++rq) {
      bf16x4 o;
#pragma unroll
      for (int i = 0; i < 4; ++i) o[i] = (bf16)(accO[md][rq * 4 + i] * invl);
      *(bf16x4*)(yp + md * 32 + rq * 8 + half * 4) = o;
    }
}

// ---------------- launch ----------------
extern "C" void kernel_launch(void* const* d_in, const int* in_sizes, int n_in,
                              void* d_out, int out_size, void* d_ws, size_t ws_size,
                              hipStream_t stream) {
  const float* x    = (const float*)d_in[0];
  const float* Wq   = (const float*)d_in[1];
  const float* Wkv  = (const float*)d_in[2];
  const float* Wout = (const float*)d_in[3];
  float* out = (float*)d_out;

  constexpr size_t NX = (size_t)2 * 2048 * 2048;  // 8388608
  constexpr size_t NW = (size_t)2048 * 2048;      // 4194304

  bf16* xb     = (bf16*)d_ws;
  bf16* wqkvb  = xb + NX;          // [6144 x 2048] = Wq rows then Wkv rows
  bf16* woutb  = wqkvb + 3 * NW;
  bf16* qk_b   = woutb + NW;       // [4096 x 4096]: q | k per row
  bf16* y_b    = qk_b + 2 * NX;
  bf16* vt_b   = y_b + NX;         // [b, f, n] = [2][2048][2048]

  cast_all_kernel<<<12288, 256, 0, stream>>>(x, Wq, Wkv, Wout, xb, wqkvb, woutb);

  // q|k = x @ [Wq; Wk]^T -> qk_b (stride 4096); one exact 256-block round
  gemm_qk_8phase<<<256, 512, 0, stream>>>(xb, wqkvb, qk_b);
  // V = x @ Wv^T -> vt_b transposed; one exact round
  gemm_thin<0><<<256, 512, 0, stream>>>(xb, wqkvb + (size_t)4096 * 2048, vt_b, nullptr);
  // attention -> y [4096, 2048] bf16
  attn_kernel<<<512, 256, 0, stream>>>(qk_b, vt_b, y_b);
  // out = y @ Wout^T : fp32; one exact round
  gemm_thin<1><<<256, 512, 0, stream>>>(y_b, woutb, nullptr, out);
}